// Round 9
// baseline (10.668 us; speedup 1.0000x reference)
//
#include <hip/hip_runtime.h>
#include <hip/hip_bf16.h>

// FWHT for 12 qubits (N=4096), batch 256, real/imag planes.
// out = FWHT(x) / 64  (H = (H2)^{⊗12}, entries ±1/64; H is never read).
//
// R4's sequential two-vector pipeline, plus:
//  1. imag loads DEFERRED until after real's round A is issued
//     (halves the entry memory burst; xi latency hides under real's
//     compute rounds). sched_barrier(0) pins the issue point.
//  2. round A starts per-chunk: each dwordx4's FWHT-4 (bits [1:0])
//     runs as that load lands (vmcnt(3-k) pipelining).
//  3. two pad-17 LDS arrays: real round-C reads overlap imag round-A
//     writes, no reuse barrier (4 barriers total).
// Radix-16 rounds over bits [3:0], [7:4], [11:8]; pad n->(n>>4)*17+(n&15)
// (proven conflict-free b32 pattern). Grid 256 = 1 block/CU, 4 waves.

#define NN 4096
#define T  256
#define PAD (NN + NN / 16)                  // 4352 floats = 17 KiB

// stages over bits [3:2] then [1:0] are interchangeable; split for
// per-chunk early start: chunk = bits [3:2], lanes bits [1:0].
__device__ __forceinline__ void fwht4_lo(float* x) {   // bits [1:0] of 4
    float a, b;
    a = x[0]; b = x[1]; x[0] = a + b; x[1] = a - b;
    a = x[2]; b = x[3]; x[2] = a + b; x[3] = a - b;
    a = x[0]; b = x[2]; x[0] = a + b; x[2] = a - b;
    a = x[1]; b = x[3]; x[1] = a + b; x[3] = a - b;
}

__device__ __forceinline__ void fwht16_hi(float x[16]) {  // bits [3:2]
#pragma unroll
    for (int s = 2; s < 4; ++s) {
        const int st = 1 << s;
#pragma unroll
        for (int i = 0; i < 16; ++i) {
            if ((i & st) == 0) {
                const float a = x[i];
                const float b = x[i + st];
                x[i]      = a + b;
                x[i + st] = a - b;
            }
        }
    }
}

__device__ __forceinline__ void fwht16(float x[16]) {
#pragma unroll
    for (int s = 0; s < 4; ++s) {
        const int st = 1 << s;
#pragma unroll
        for (int i = 0; i < 16; ++i) {
            if ((i & st) == 0) {
                const float a = x[i];
                const float b = x[i + st];
                x[i]      = a + b;
                x[i + st] = a - b;
            }
        }
    }
}

__global__ __launch_bounds__(T)
void fwht_kernel(const float* __restrict__ gr,
                 const float* __restrict__ gi,
                 float* __restrict__ out) {
    __shared__ float sr[PAD];
    __shared__ float si[PAD];

    const int b = blockIdx.x;               // batch 0..255
    const int t = threadIdx.x;              // 0..255

    const float4* pr = (const float4*)(gr + (size_t)b * NN + t * 16);
    const float4* pi = (const float4*)(gi + (size_t)b * NN + t * 16);
    float*        dr = out + (size_t)b * NN;
    float*        di = out + (size_t)(256 + b) * NN;

    const int baseB = (t >> 4) * 272 + (t & 15);   // bits [7:4] gather
    const int baseC = (t >> 4) * 17 + (t & 15);    // bits [11:8] gather
    const float sc = 0.015625f;                    // (1/sqrt(2))^12

    // ---- real loads only; round A chunk-pipelined as data lands ----
    float xr[16];
#pragma unroll
    for (int k = 0; k < 4; ++k) {
        const float4 r = pr[k];
        xr[4 * k + 0] = r.x; xr[4 * k + 1] = r.y;
        xr[4 * k + 2] = r.z; xr[4 * k + 3] = r.w;
        fwht4_lo(&xr[4 * k]);               // bits [1:0], waits vmcnt(3-k)
    }
    fwht16_hi(xr);                          // bits [3:2]
#pragma unroll
    for (int r = 0; r < 16; ++r) sr[t * 17 + r] = xr[r];

    // ---- NOW issue imag loads (pinned here; hide under real compute) ----
    __builtin_amdgcn_sched_barrier(0);
    float xi[16];
#pragma unroll
    for (int k = 0; k < 4; ++k) {
        const float4 i = pi[k];
        xi[4 * k + 0] = i.x; xi[4 * k + 1] = i.y;
        xi[4 * k + 2] = i.z; xi[4 * k + 3] = i.w;
    }
    __builtin_amdgcn_sched_barrier(0);

    __syncthreads();                        // bar1: A_r visible

    // ---- B_r: bits [7:4] ----
#pragma unroll
    for (int q = 0; q < 16; ++q) xr[q] = sr[baseB + q * 17];
    fwht16(xr);
#pragma unroll
    for (int q = 0; q < 16; ++q) sr[baseB + q * 17] = xr[q];  // same addrs
    __syncthreads();                        // bar2: B_r visible

    // ---- C_r + store_r; A_i writes to si overlap (separate array) ----
#pragma unroll
    for (int p = 0; p < 16; ++p) xr[p] = sr[baseC + p * 272];
    fwht16(xr);
#pragma unroll
    for (int p = 0; p < 16; ++p) dr[p * 256 + t] = xr[p] * sc;

    fwht16(xi);                             // A_i (xi landed long ago)
#pragma unroll
    for (int r = 0; r < 16; ++r) si[t * 17 + r] = xi[r];
    __syncthreads();                        // bar3: A_i visible

    // ---- B_i ----
#pragma unroll
    for (int q = 0; q < 16; ++q) xi[q] = si[baseB + q * 17];
    fwht16(xi);
#pragma unroll
    for (int q = 0; q < 16; ++q) si[baseB + q * 17] = xi[q];
    __syncthreads();                        // bar4: B_i visible

    // ---- C_i + store_i ----
#pragma unroll
    for (int p = 0; p < 16; ++p) xi[p] = si[baseC + p * 272];
    fwht16(xi);
#pragma unroll
    for (int p = 0; p < 16; ++p) di[p * 256 + t] = xi[p] * sc;
}

extern "C" void kernel_launch(void* const* d_in, const int* in_sizes, int n_in,
                              void* d_out, int out_size, void* d_ws, size_t ws_size,
                              hipStream_t stream) {
    const float* gr = (const float*)d_in[0];
    const float* gi = (const float*)d_in[1];
    float* out = (float*)d_out;

    fwht_kernel<<<256, T, 0, stream>>>(gr, gi, out);
}

// Round 10
// 10.139 us; speedup vs baseline: 1.0521x; 1.0521x over previous
//
#include <hip/hip_runtime.h>
#include <hip/hip_bf16.h>

// FWHT for 12 qubits (N=4096), batch 256, real/imag planes.
// out = FWHT(x) / 64  (H = (H2)^{⊗12}, entries ±1/64; H is never read).
//
// R4 (best measured: 9.90us) verbatim, with ONE change: two separate
// pad-17 LDS arrays so the inter-vector reuse barrier is deleted
// (5 barriers -> 4). v1's round-C reads hit sr while v2's round-A
// writes hit si — no false coupling, waves flow straight through.
// Radix-16 rounds over bits [3:0], [7:4], [11:8]; pad n->(n>>4)*17+(n&15)
// (proven conflict-free b32 pattern). Grid 256 = 1 block/CU, 4 waves.
// Both planes' loads issue at entry (one latency covers everything);
// v1's stores drain under v2's compute (R4's proven overlap).

#define NN 4096
#define T  256
#define PAD (NN + NN / 16)                  // 4352 floats = 17 KiB

__device__ __forceinline__ void fwht16(float x[16]) {
#pragma unroll
    for (int s = 0; s < 4; ++s) {
        const int st = 1 << s;
#pragma unroll
        for (int i = 0; i < 16; ++i) {
            if ((i & st) == 0) {
                const float a = x[i];
                const float b = x[i + st];
                x[i]      = a + b;
                x[i + st] = a - b;
            }
        }
    }
}

__global__ __launch_bounds__(T)
void fwht_kernel(const float* __restrict__ gr,
                 const float* __restrict__ gi,
                 float* __restrict__ out) {
    __shared__ float sr[PAD];
    __shared__ float si[PAD];

    const int b = blockIdx.x;               // batch 0..255
    const int t = threadIdx.x;              // 0..255

    const float4* pr = (const float4*)(gr + (size_t)b * NN + t * 16);
    const float4* pi = (const float4*)(gi + (size_t)b * NN + t * 16);
    float*        dr = out + (size_t)b * NN;
    float*        di = out + (size_t)(256 + b) * NN;

    const int baseB = (t >> 4) * 272 + (t & 15);   // bits [7:4] gather
    const int baseC = (t >> 4) * 17 + (t & 15);    // bits [11:8] gather
    const float sc = 0.015625f;                    // (1/sqrt(2))^12

    // ---- all loads issue at entry (8x dwordx4/thread) ----
    float xr[16], xi[16];
#pragma unroll
    for (int k = 0; k < 4; ++k) {
        const float4 r = pr[k];
        xr[4 * k + 0] = r.x; xr[4 * k + 1] = r.y;
        xr[4 * k + 2] = r.z; xr[4 * k + 3] = r.w;
    }
#pragma unroll
    for (int k = 0; k < 4; ++k) {
        const float4 i = pi[k];
        xi[4 * k + 0] = i.x; xi[4 * k + 1] = i.y;
        xi[4 * k + 2] = i.z; xi[4 * k + 3] = i.w;
    }

    // ======== vector 1: real ========
    // ---- A_r: bits [3:0] (thread t owns n = t*16 + r) ----
    fwht16(xr);
#pragma unroll
    for (int r = 0; r < 16; ++r) sr[t * 17 + r] = xr[r];
    __syncthreads();                        // bar1

    // ---- B_r: bits [7:4] ----
#pragma unroll
    for (int q = 0; q < 16; ++q) xr[q] = sr[baseB + q * 17];
    fwht16(xr);
#pragma unroll
    for (int q = 0; q < 16; ++q) sr[baseB + q * 17] = xr[q];  // same addrs
    __syncthreads();                        // bar2

    // ---- C_r + store_r ----
#pragma unroll
    for (int p = 0; p < 16; ++p) xr[p] = sr[baseC + p * 272];
    fwht16(xr);
#pragma unroll
    for (int p = 0; p < 16; ++p) dr[p * 256 + t] = xr[p] * sc;

    // ======== vector 2: imag (no barrier needed: separate array) ========
    // ---- A_i ----
    fwht16(xi);
#pragma unroll
    for (int r = 0; r < 16; ++r) si[t * 17 + r] = xi[r];
    __syncthreads();                        // bar3

    // ---- B_i ----
#pragma unroll
    for (int q = 0; q < 16; ++q) xi[q] = si[baseB + q * 17];
    fwht16(xi);
#pragma unroll
    for (int q = 0; q < 16; ++q) si[baseB + q * 17] = xi[q];  // same addrs
    __syncthreads();                        // bar4

    // ---- C_i + store_i ----
#pragma unroll
    for (int p = 0; p < 16; ++p) xi[p] = si[baseC + p * 272];
    fwht16(xi);
#pragma unroll
    for (int p = 0; p < 16; ++p) di[p * 256 + t] = xi[p] * sc;
}

extern "C" void kernel_launch(void* const* d_in, const int* in_sizes, int n_in,
                              void* d_out, int out_size, void* d_ws, size_t ws_size,
                              hipStream_t stream) {
    const float* gr = (const float*)d_in[0];
    const float* gi = (const float*)d_in[1];
    float* out = (float*)d_out;

    fwht_kernel<<<256, T, 0, stream>>>(gr, gi, out);
}